// Round 7
// baseline (290.623 us; speedup 1.0000x reference)
//
#include <hip/hip_runtime.h>
#include <hip/hip_bf16.h>

#define B_    32
#define CIN   128
#define COUT  128
#define NN    128
#define PPAD  130                   // padded p dimension (1 zero col each side)
#define ROWE  (PPAD * CIN)          // 16640 ushorts per padded xT row
#define CHROW7 (PPAD * 16)          // 2080 16B chunks per full padded row
#define CH7    (4 * CHROW7)         // 8320 chunks per block tile (4 rows)

typedef __attribute__((ext_vector_type(8))) short short8;
typedef __attribute__((ext_vector_type(4))) float float4v;

static __device__ inline unsigned short f2bf(float f) {
    union { float f; unsigned u; } v; v.f = f;
    unsigned u = v.u;
    unsigned r = u + 0x7FFFu + ((u >> 16) & 1u);   // RNE
    return (unsigned short)(r >> 16);
}

// async 16B global->LDS copy (dest: readfirstlane(base)+lane*16 — callers
// MUST keep the branch wave-uniform)
static __device__ inline void gll16(const unsigned short* g, unsigned short* l) {
    __builtin_amdgcn_global_load_lds((const __attribute__((address_space(1))) unsigned int*)g,
                                     (__attribute__((address_space(3))) unsigned int*)l,
                                     16, 0, 0);
}

// ---------------------------------------------------------------------------
// x [B][C][N][N] f32 -> xT [B][row][PPAD][128c] bf16, PRE-SWIZZLED:
// 16B chunk at (pp, slot j) holds channels (j ^ (pp&15))*8 .. +7.
// zero cols pp=0,129. One block per (b,row).
// ---------------------------------------------------------------------------
__global__ __launch_bounds__(256) void xpose_kernel(const float* __restrict__ x,
                                                    unsigned short* __restrict__ xT) {
    int b = blockIdx.x >> 7;
    int i = blockIdx.x & 127;
    __shared__ unsigned short tile[CIN * PPAD];   // [c][p], row stride 130
    int tid = threadIdx.x;
    const float* src = x + ((size_t)(b * CIN) * NN + i) * NN;  // x[b][0][i][0]
    #pragma unroll
    for (int e = 0; e < 64; ++e) {
        int idx = e * 256 + tid;
        int c = idx >> 7;
        int p = idx & 127;
        tile[c * PPAD + p] = f2bf(src[(size_t)c * (NN * NN) + p]);
    }
    __syncthreads();
    unsigned short* dst = xT + (size_t)(b * NN + i) * ROWE;
    #pragma unroll
    for (int e = 0; e < 32; ++e) {
        int pi = e * 256 + tid;          // 0..8191
        int c2 = (pi & 63) * 2;
        int p  = pi >> 6;
        ushort2 v;
        v.x = tile[c2 * PPAD + p];
        v.y = tile[(c2 + 1) * PPAD + p];
        int pp = p + 1;
        int sl = (c2 >> 3) ^ (pp & 15);              // baked XOR swizzle
        *(ushort2*)(dst + (size_t)pp * CIN + sl * 8 + (c2 & 7)) = v;
    }
    if (tid < 128) {                                  // zero pad cols
        dst[tid] = 0;
        dst[(size_t)129 * CIN + tid] = 0;
    }
}

// ---------------------------------------------------------------------------
// kernel [O][C][3][3] f32 -> kT2 [kd][cslot16][o][8c] bf16  (kd = k*3+d)
// ---------------------------------------------------------------------------
__global__ __launch_bounds__(256) void ktrans_kernel(const float* __restrict__ kern,
                                                     unsigned short* __restrict__ kT2) {
    int idx = blockIdx.x * 256 + threadIdx.x;     // 0..147455
    if (idx >= COUT * CIN * 9) return;
    int c  = idx & 127;
    int o  = (idx >> 7) & 127;
    int kd = idx >> 14;                           // 0..8
    int k = kd / 3, d = kd % 3;
    float v = kern[(((size_t)o * CIN + c) * 3 + k) * 3 + d];
    kT2[((size_t)(kd * 16 + (c >> 3)) * 128 + o) * 8 + (c & 7)] = f2bf(v);
}

// ---------------------------------------------------------------------------
// main v7: block = 2 output rows x 128 px x 128 o (v2 geometry + v6 tech).
// 512 thr (8 waves), LDS = 4 full padded rows = 133 KB -> 1 block/CU.
// x staged ONCE via async global_load_lds (linear: LDS layout == xT layout);
// wave tile: 64 o x 64 px x 1 row -> A-traffic halved vs v6 (2.36 GB L2).
// ---------------------------------------------------------------------------
__global__ __launch_bounds__(512, 2) void conv_mfma7_kernel(const unsigned short* __restrict__ xT,
                                                            const unsigned short* __restrict__ kT2,
                                                            float* __restrict__ out) {
    __shared__ unsigned short xs[4 * ROWE];   // 133,120 B

    // bijective XCD swizzle: 2048 blocks, 8 XCDs, 256-block contiguous slabs
    int wg = blockIdx.x;
    int lb = (wg & 7) * 256 + (wg >> 3);
    int b  = lb >> 6;            // image
    int rp = lb & 63;            // row pair

    int tid  = threadIdx.x;
    int lane = tid & 63;
    int wave = tid >> 6;
    int wo = wave >> 2;            // o half (0/1)
    int wr = (wave >> 1) & 1;      // row of pair
    int wq = wave & 1;             // px 64-half
    int ob  = wo * 64;
    int pb  = wq * 64;
    int l15 = lane & 15;
    int lg  = lane >> 4;           // 0..3

    // ---- stage 4 full x-rows (rp*2-1 .. rp*2+2) once, rows clamped ----
    {
        const unsigned short* xrow_base = xT + (size_t)b * NN * ROWE;
        #pragma unroll
        for (int s = 0; s < 17; ++s) {
            int W = s * 512 + tid;
            if (W < CH7) {                       // 8320 = 130 full waves
                int r    = W / CHROW7;           // 0..3
                int rem  = W - r * CHROW7;       // chunk within row (= xT chunk idx)
                int grow = rp * 2 - 1 + r;       // -1..128
                int growc = grow < 0 ? 0 : (grow > NN - 1 ? NN - 1 : grow);
                gll16(xrow_base + (size_t)growc * ROWE + (size_t)rem * 8,
                      xs + (size_t)W * 8);
            }
        }
    }
    __syncthreads();   // drains vmcnt -> staged data visible

    // ---- zero halo rows outside the image (block-uniform branches) ----
    if (rp == 0) {
        for (int W = tid; W < CHROW7; W += 512)                    // row r=0
            *(short8*)(xs + (size_t)W * 8) = (short8)(0);
    }
    if (rp == 63) {
        for (int W = 3 * CHROW7 + tid; W < 4 * CHROW7; W += 512)   // row r=3
            *(short8*)(xs + (size_t)W * 8) = (short8)(0);
    }
    if (rp == 0 || rp == 63) __syncthreads();

    float4v acc[4][4];
    #pragma unroll
    for (int m = 0; m < 4; ++m)
        #pragma unroll
        for (int n = 0; n < 4; ++n)
            acc[m][n] = (float4v)(0.0f);

    #pragma unroll
    for (int kd = 0; kd < 9; ++kd) {
        const int k = kd / 3, d = kd % 3;
        const unsigned short* srow = xs + (size_t)(wr + k) * ROWE;   // LDS row
        #pragma unroll
        for (int cc = 0; cc < 4; ++cc) {
            const int cslot = cc * 4 + lg;
            short8 a[4], bt[4];
            #pragma unroll
            for (int m = 0; m < 4; ++m)
                a[m] = *(const short8*)(kT2 +
                    ((size_t)((kd * 16 + cslot) * 128) + ob + m * 16 + l15) * 8);
            #pragma unroll
            for (int n = 0; n < 4; ++n) {
                int pp = pb + n * 16 + l15 + d;          // 0..129 (always valid)
                bt[n] = *(const short8*)(srow + ((size_t)pp * 16 + (cslot ^ (pp & 15))) * 8);
            }
            #pragma unroll
            for (int m = 0; m < 4; ++m)
                #pragma unroll
                for (int n = 0; n < 4; ++n)
                    acc[m][n] = __builtin_amdgcn_mfma_f32_16x16x32_bf16(a[m], bt[n], acc[m][n], 0, 0, 0);
        }
    }

    // store: D col = lane&15 -> px, row = (lane>>4)*4 + r -> o
    int row = rp * 2 + wr;
    float* op = out + (size_t)b * COUT * NN * NN + (size_t)row * NN;
    #pragma unroll
    for (int m = 0; m < 4; ++m) {
        #pragma unroll
        for (int n = 0; n < 4; ++n) {
            int p = pb + n * 16 + l15;
            #pragma unroll
            for (int r = 0; r < 4; ++r) {
                int o = ob + m * 16 + lg * 4 + r;
                op[(size_t)o * (NN * NN) + p] = acc[m][n][r];
            }
        }
    }
}

// ---------------------------------------------------------------------------
// fallback: naive direct conv (only if workspace too small)
// ---------------------------------------------------------------------------
__global__ __launch_bounds__(256) void conv_naive_kernel(const float* __restrict__ x,
                                                         const float* __restrict__ kern,
                                                         float* __restrict__ out) {
    size_t idx = (size_t)blockIdx.x * 256 + threadIdx.x;
    int p = idx & 127;
    size_t t = idx >> 7;
    int i = t & 127; t >>= 7;
    int o = t & 127;
    int b = (int)(t >> 7);
    float s = 0.f;
    for (int c = 0; c < CIN; ++c) {
        #pragma unroll
        for (int k = 0; k < 3; ++k) {
            int r = i + k - 1;
            if (r < 0 || r >= NN) continue;
            #pragma unroll
            for (int d = 0; d < 3; ++d) {
                int q = p + d - 1;
                if (q < 0 || q >= NN) continue;
                s += kern[(((size_t)o * CIN + c) * 3 + k) * 3 + d]
                   * x[(((size_t)b * CIN + c) * NN + r) * NN + q];
            }
        }
    }
    out[idx] = s;
}

extern "C" void kernel_launch(void* const* d_in, const int* in_sizes, int n_in,
                              void* d_out, int out_size, void* d_ws, size_t ws_size,
                              hipStream_t stream) {
    const float* x    = (const float*)d_in[0];
    const float* kern = (const float*)d_in[1];
    float* out = (float*)d_out;

    const size_t xT_bytes  = (size_t)B_ * NN * ROWE * 2;        // 136,314,880
    const size_t kT_bytes  = (size_t)9 * 16 * 128 * 8 * 2;      //     294,912

    if (ws_size >= xT_bytes + kT_bytes) {
        unsigned short* xT  = (unsigned short*)d_ws;
        unsigned short* kT2 = (unsigned short*)((char*)d_ws + xT_bytes);
        hipLaunchKernelGGL(xpose_kernel, dim3(B_ * NN), dim3(256), 0, stream, x, xT);
        hipLaunchKernelGGL(ktrans_kernel, dim3(576), dim3(256), 0, stream, kern, kT2);
        hipLaunchKernelGGL(conv_mfma7_kernel, dim3(2048), dim3(512), 0, stream, xT, kT2, out);
    } else {
        hipLaunchKernelGGL(conv_naive_kernel, dim3(67108864 / 256), dim3(256), 0, stream,
                           x, kern, out);
    }
}

// Round 8
// 258.933 us; speedup vs baseline: 1.1224x; 1.1224x over previous
//
#include <hip/hip_runtime.h>
#include <hip/hip_bf16.h>

#define B_    32
#define CIN   128
#define COUT  128
#define NN    128
#define PPAD  130                   // padded p dimension in xT (1 zero col each side)
#define ROWE  (PPAD * CIN)          // 16640 ushorts per padded xT row
#define XCH   8192                  // x chunks in LDS: 4 rows * 128 px * 16 slots
#define ACH   512                   // chunks per A slice: 4 cslots * 128 o

typedef __attribute__((ext_vector_type(8))) short short8;
typedef __attribute__((ext_vector_type(4))) float float4v;

static __device__ inline unsigned short f2bf(float f) {
    union { float f; unsigned u; } v; v.f = f;
    unsigned u = v.u;
    unsigned r = u + 0x7FFFu + ((u >> 16) & 1u);   // RNE
    return (unsigned short)(r >> 16);
}

// async 16B global->LDS copy (dest = firstlane base + lane*16; keep issue
// wave-uniform, no divergence)
static __device__ inline void gll16(const unsigned short* g, unsigned short* l) {
    __builtin_amdgcn_global_load_lds((const __attribute__((address_space(1))) unsigned int*)g,
                                     (__attribute__((address_space(3))) unsigned int*)l,
                                     16, 0, 0);
}

// ---------------------------------------------------------------------------
// x [B][C][N][N] f32 -> xT [B][row][PPAD][128c] bf16, PRE-SWIZZLED:
// 16B chunk at (pp, slot j) holds channels (j ^ (pp&15))*8 .. +7.
// zero cols pp=0,129. One block per (b,row).
// ---------------------------------------------------------------------------
__global__ __launch_bounds__(256) void xpose_kernel(const float* __restrict__ x,
                                                    unsigned short* __restrict__ xT) {
    int b = blockIdx.x >> 7;
    int i = blockIdx.x & 127;
    __shared__ unsigned short tile[CIN * PPAD];   // [c][p], row stride 130
    int tid = threadIdx.x;
    const float* src = x + ((size_t)(b * CIN) * NN + i) * NN;  // x[b][0][i][0]
    #pragma unroll
    for (int e = 0; e < 64; ++e) {
        int idx = e * 256 + tid;
        int c = idx >> 7;
        int p = idx & 127;
        tile[c * PPAD + p] = f2bf(src[(size_t)c * (NN * NN) + p]);
    }
    __syncthreads();
    unsigned short* dst = xT + (size_t)(b * NN + i) * ROWE;
    #pragma unroll
    for (int e = 0; e < 32; ++e) {
        int pi = e * 256 + tid;          // 0..8191
        int c2 = (pi & 63) * 2;
        int p  = pi >> 6;
        ushort2 v;
        v.x = tile[c2 * PPAD + p];
        v.y = tile[(c2 + 1) * PPAD + p];
        int pp = p + 1;
        int sl = (c2 >> 3) ^ (pp & 15);              // baked XOR swizzle
        *(ushort2*)(dst + (size_t)pp * CIN + sl * 8 + (c2 & 7)) = v;
    }
    if (tid < 128) {                                  // zero pad cols
        dst[tid] = 0;
        dst[(size_t)129 * CIN + tid] = 0;
    }
}

// ---------------------------------------------------------------------------
// kernel [O][C][3][3] f32 -> kT2 [kd][cslot16][o][8c] bf16  (kd = k*3+d)
// chunk index = (kd*16+cslot)*128 + o; slice ph=(kd*4+cc) = chunks [ph*512,+512)
// ---------------------------------------------------------------------------
__global__ __launch_bounds__(256) void ktrans_kernel(const float* __restrict__ kern,
                                                     unsigned short* __restrict__ kT2) {
    int idx = blockIdx.x * 256 + threadIdx.x;     // 0..147455
    if (idx >= COUT * CIN * 9) return;
    int c  = idx & 127;
    int o  = (idx >> 7) & 127;
    int kd = idx >> 14;                           // 0..8
    int k = kd / 3, d = kd % 3;
    float v = kern[(((size_t)o * CIN + c) * 3 + k) * 3 + d];
    kT2[((size_t)(kd * 16 + (c >> 3)) * 128 + o) * 8 + (c & 7)] = f2bf(v);
}

// ---------------------------------------------------------------------------
// main v8: block = 2 rows x 128 px x 128 o. 512 thr (8 waves). FULL-LDS inner
// loop: x tile (4 rows x 128 px x 128 c, NO pad cols -> edge cndmask) = 128 KB
// + kT2 in 36 phases of 8 KB slices, TRIPLE-buffered (24 KB) via async
// global_load_lds two phases ahead. Counted vmcnt(1) before each raw
// s_barrier (never 0); setprio around MFMA cluster. 152 KB LDS, 1 block/CU.
// ---------------------------------------------------------------------------
__global__ __launch_bounds__(512, 1) void conv_mfma8_kernel(const unsigned short* __restrict__ xT,
                                                            const unsigned short* __restrict__ kT2,
                                                            float* __restrict__ out) {
    __shared__ unsigned short xs[(XCH + 3 * ACH) * 8];   // 155,648 B

    // bijective XCD swizzle: 2048 blocks, 8 XCDs, 256-block contiguous slabs
    int wg = blockIdx.x;
    int lb = (wg & 7) * 256 + (wg >> 3);
    int b  = lb >> 6;            // image
    int rp = lb & 63;            // row pair

    int tid  = threadIdx.x;
    int lane = tid & 63;
    int wave = tid >> 6;
    int wo = wave >> 2;            // o half (0/1)
    int wr = (wave >> 1) & 1;      // row of pair
    int wq = wave & 1;             // px 64-half
    int ob  = wo * 64;
    int pb  = wq * 64;
    int l15 = lane & 15;
    int lg  = lane >> 4;           // 0..3

    // ---- prologue: stage x tile (16 chunks/thread) + A slices 0,1 ----
    {
        const unsigned short* xrow_base = xT + (size_t)b * NN * ROWE;
        #pragma unroll
        for (int s = 0; s < 16; ++s) {
            int W   = s * 512 + tid;            // 0..8191
            int r   = W >> 11;                  // 0..3
            int rem = W & 2047;                 // p*16 + j
            int grow = rp * 2 - 1 + r;          // -1..128
            int growc = grow < 0 ? 0 : (grow > NN - 1 ? NN - 1 : grow);
            // src chunk = (p+1)*16 + j = rem + 16  (skip pad col 0)
            gll16(xrow_base + (size_t)growc * ROWE + (size_t)(rem + 16) * 8,
                  xs + (size_t)W * 8);
        }
        gll16(kT2 + (size_t)tid * 8,         xs + (size_t)(XCH + tid) * 8);
        gll16(kT2 + (size_t)(ACH + tid) * 8, xs + (size_t)(XCH + ACH + tid) * 8);
    }
    asm volatile("s_waitcnt vmcnt(1)" ::: "memory");   // x + slice0 landed; slice1 flying
    __builtin_amdgcn_s_barrier();

    // ---- zero halo rows outside the image (block-uniform) ----
    if (rp == 0) {
        for (int W = tid; W < 2048; W += 512)
            *(short8*)(xs + (size_t)W * 8) = (short8)(0);
    }
    if (rp == 63) {
        for (int W = 3 * 2048 + tid; W < 4 * 2048; W += 512)
            *(short8*)(xs + (size_t)W * 8) = (short8)(0);
    }
    if (rp == 0 || rp == 63) {
        asm volatile("s_waitcnt lgkmcnt(0)" ::: "memory");
        __builtin_amdgcn_s_barrier();
    }

    float4v acc[4][4];
    #pragma unroll
    for (int m = 0; m < 4; ++m)
        #pragma unroll
        for (int n = 0; n < 4; ++n)
            acc[m][n] = (float4v)(0.0f);

    // ---- 36 phases: phase ph = (kd, cc); buf[ph%3] holds slice ph ----
    #pragma unroll
    for (int kd = 0; kd < 9; ++kd) {
        const int k = kd / 3, d = kd % 3;
        #pragma unroll
        for (int cc = 0; cc < 4; ++cc) {
            const int ph = kd * 4 + cc;
            short8 a[4], bt[4];
            // A-frags from LDS slice buffer
            const unsigned short* ab = xs + (size_t)(XCH + (ph % 3) * ACH) * 8;
            #pragma unroll
            for (int m = 0; m < 4; ++m)
                a[m] = *(const short8*)(ab + ((size_t)lg * 128 + ob + m * 16 + l15) * 8);
            // B-frags from x tile with p-edge masking
            const unsigned short* srow = xs + (size_t)(wr + k) * 2048 * 8;
            #pragma unroll
            for (int n = 0; n < 4; ++n) {
                int q  = pb + n * 16 + l15 + d - 1;          // -1..128 (unpadded)
                int qc = q < 0 ? 0 : (q > 127 ? 127 : q);
                int j  = (cc * 4 + lg) ^ ((qc + 1) & 15);
                short8 v = *(const short8*)(srow + ((size_t)qc * 16 + j) * 8);
                bt[n] = (q < 0 || q > 127) ? (short8)(0) : v;
            }
            // issue stage of slice ph+2 (tail: re-stage 35, benign dup)
            {
                const int pn = (ph + 2 > 35) ? 35 : (ph + 2);
                gll16(kT2 + ((size_t)pn * ACH + tid) * 8,
                      xs + (size_t)(XCH + (pn % 3) * ACH + tid) * 8);
            }
            __builtin_amdgcn_s_setprio(1);
            #pragma unroll
            for (int m = 0; m < 4; ++m)
                #pragma unroll
                for (int n = 0; n < 4; ++n)
                    acc[m][n] = __builtin_amdgcn_mfma_f32_16x16x32_bf16(a[m], bt[n], acc[m][n], 0, 0, 0);
            __builtin_amdgcn_s_setprio(0);
            // slice ph+1 (issued at ph-1) must land before next phase reads it
            asm volatile("s_waitcnt vmcnt(1)" ::: "memory");
            __builtin_amdgcn_s_barrier();
        }
    }

    // store: D col = lane&15 -> px, row = (lane>>4)*4 + r -> o
    int row = rp * 2 + wr;
    float* op = out + (size_t)b * COUT * NN * NN + (size_t)row * NN;
    #pragma unroll
    for (int m = 0; m < 4; ++m) {
        #pragma unroll
        for (int n = 0; n < 4; ++n) {
            int p = pb + n * 16 + l15;
            #pragma unroll
            for (int r = 0; r < 4; ++r) {
                int o = ob + m * 16 + lg * 4 + r;
                op[(size_t)o * (NN * NN) + p] = acc[m][n][r];
            }
        }
    }
}

// ---------------------------------------------------------------------------
// fallback: naive direct conv (only if workspace too small)
// ---------------------------------------------------------------------------
__global__ __launch_bounds__(256) void conv_naive_kernel(const float* __restrict__ x,
                                                         const float* __restrict__ kern,
                                                         float* __restrict__ out) {
    size_t idx = (size_t)blockIdx.x * 256 + threadIdx.x;
    int p = idx & 127;
    size_t t = idx >> 7;
    int i = t & 127; t >>= 7;
    int o = t & 127;
    int b = (int)(t >> 7);
    float s = 0.f;
    for (int c = 0; c < CIN; ++c) {
        #pragma unroll
        for (int k = 0; k < 3; ++k) {
            int r = i + k - 1;
            if (r < 0 || r >= NN) continue;
            #pragma unroll
            for (int d = 0; d < 3; ++d) {
                int q = p + d - 1;
                if (q < 0 || q >= NN) continue;
                s += kern[(((size_t)o * CIN + c) * 3 + k) * 3 + d]
                   * x[(((size_t)b * CIN + c) * NN + r) * NN + q];
            }
        }
    }
    out[idx] = s;
}

extern "C" void kernel_launch(void* const* d_in, const int* in_sizes, int n_in,
                              void* d_out, int out_size, void* d_ws, size_t ws_size,
                              hipStream_t stream) {
    const float* x    = (const float*)d_in[0];
    const float* kern = (const float*)d_in[1];
    float* out = (float*)d_out;

    const size_t xT_bytes  = (size_t)B_ * NN * ROWE * 2;        // 136,314,880
    const size_t kT_bytes  = (size_t)9 * 16 * 128 * 8 * 2;      //     294,912

    if (ws_size >= xT_bytes + kT_bytes) {
        unsigned short* xT  = (unsigned short*)d_ws;
        unsigned short* kT2 = (unsigned short*)((char*)d_ws + xT_bytes);
        hipLaunchKernelGGL(xpose_kernel, dim3(B_ * NN), dim3(256), 0, stream, x, xT);
        hipLaunchKernelGGL(ktrans_kernel, dim3(576), dim3(256), 0, stream, kern, kT2);
        hipLaunchKernelGGL(conv_mfma8_kernel, dim3(2048), dim3(512), 0, stream, xT, kT2, out);
    } else {
        hipLaunchKernelGGL(conv_naive_kernel, dim3(67108864 / 256), dim3(256), 0, stream,
                           x, kern, out);
    }
}

// Round 9
// 255.301 us; speedup vs baseline: 1.1384x; 1.0142x over previous
//
#include <hip/hip_runtime.h>
#include <hip/hip_bf16.h>

#define B_    32
#define CIN   128
#define COUT  128
#define NN    128
#define PPAD  130                   // padded p dimension in xT (1 zero col each side)
#define ROWE  (PPAD * CIN)          // 16640 ushorts per padded xT row
#define XCH   8192                  // x chunks in LDS: 4 rows * 128 px * 16 slots
#define ACH   512                   // chunks per A slice: 4 cslots * 128 o

typedef __attribute__((ext_vector_type(8))) short short8;
typedef __attribute__((ext_vector_type(4))) float float4v;

static __device__ inline unsigned short f2bf(float f) {
    union { float f; unsigned u; } v; v.f = f;
    unsigned u = v.u;
    unsigned r = u + 0x7FFFu + ((u >> 16) & 1u);   // RNE
    return (unsigned short)(r >> 16);
}

// async 16B global->LDS copy (dest = firstlane base + lane*16; keep issue
// wave-uniform, no divergence)
static __device__ inline void gll16(const unsigned short* g, unsigned short* l) {
    __builtin_amdgcn_global_load_lds((const __attribute__((address_space(1))) unsigned int*)g,
                                     (__attribute__((address_space(3))) unsigned int*)l,
                                     16, 0, 0);
}

// ---------------------------------------------------------------------------
// x [B][C][N][N] f32 -> xT [B][row][PPAD][128c] bf16, PRE-SWIZZLED:
// 16B chunk at (pp, slot j) holds channels (j ^ (pp&15))*8 .. +7.
// zero cols pp=0,129. One block per (b,row).
// ---------------------------------------------------------------------------
__global__ __launch_bounds__(256) void xpose_kernel(const float* __restrict__ x,
                                                    unsigned short* __restrict__ xT) {
    int b = blockIdx.x >> 7;
    int i = blockIdx.x & 127;
    __shared__ unsigned short tile[CIN * PPAD];   // [c][p], row stride 130
    int tid = threadIdx.x;
    const float* src = x + ((size_t)(b * CIN) * NN + i) * NN;  // x[b][0][i][0]
    #pragma unroll
    for (int e = 0; e < 64; ++e) {
        int idx = e * 256 + tid;
        int c = idx >> 7;
        int p = idx & 127;
        tile[c * PPAD + p] = f2bf(src[(size_t)c * (NN * NN) + p]);
    }
    __syncthreads();
    unsigned short* dst = xT + (size_t)(b * NN + i) * ROWE;
    #pragma unroll
    for (int e = 0; e < 32; ++e) {
        int pi = e * 256 + tid;          // 0..8191
        int c2 = (pi & 63) * 2;
        int p  = pi >> 6;
        ushort2 v;
        v.x = tile[c2 * PPAD + p];
        v.y = tile[(c2 + 1) * PPAD + p];
        int pp = p + 1;
        int sl = (c2 >> 3) ^ (pp & 15);              // baked XOR swizzle
        *(ushort2*)(dst + (size_t)pp * CIN + sl * 8 + (c2 & 7)) = v;
    }
    if (tid < 128) {                                  // zero pad cols
        dst[tid] = 0;
        dst[(size_t)129 * CIN + tid] = 0;
    }
}

// ---------------------------------------------------------------------------
// kernel [O][C][3][3] f32 -> kT2 [kd][cslot16][o][8c] bf16  (kd = k*3+d)
// chunk index = (kd*16+cslot)*128 + o; slice ph=(kd*4+cc) = chunks [ph*512,+512)
// ---------------------------------------------------------------------------
__global__ __launch_bounds__(256) void ktrans_kernel(const float* __restrict__ kern,
                                                     unsigned short* __restrict__ kT2) {
    int idx = blockIdx.x * 256 + threadIdx.x;     // 0..147455
    if (idx >= COUT * CIN * 9) return;
    int c  = idx & 127;
    int o  = (idx >> 7) & 127;
    int kd = idx >> 14;                           // 0..8
    int k = kd / 3, d = kd % 3;
    float v = kern[(((size_t)o * CIN + c) * 3 + k) * 3 + d];
    kT2[((size_t)(kd * 16 + (c >> 3)) * 128 + o) * 8 + (c & 7)] = f2bf(v);
}

// ---------------------------------------------------------------------------
// main v9: v8 + register double-buffered fragments (prefetch phase ph+1's
// ds_reads under phase ph's MFMAs) + 4-deep A-slice gll16 pipeline
// (issue slice ph+3 in phase ph; vmcnt(1) at phase end drains ph+2).
// LDS = x-tile 128 KB + 4x8 KB A slices = 163,840 B (full 160 KiB).
// ---------------------------------------------------------------------------
__global__ __launch_bounds__(512, 1) void conv_mfma9_kernel(const unsigned short* __restrict__ xT,
                                                            const unsigned short* __restrict__ kT2,
                                                            float* __restrict__ out) {
    __shared__ unsigned short xs[(XCH + 4 * ACH) * 8];   // 163,840 B

    // bijective XCD swizzle: 2048 blocks, 8 XCDs, 256-block contiguous slabs
    int wg = blockIdx.x;
    int lb = (wg & 7) * 256 + (wg >> 3);
    int b  = lb >> 6;            // image
    int rp = lb & 63;            // row pair

    int tid  = threadIdx.x;
    int lane = tid & 63;
    int wave = tid >> 6;
    int wo = wave >> 2;            // o half (0/1)
    int wr = (wave >> 1) & 1;      // row of pair
    int wq = wave & 1;             // px 64-half
    int ob  = wo * 64;
    int pb  = wq * 64;
    int l15 = lane & 15;
    int lg  = lane >> 4;           // 0..3

    // ---- prologue: stage x tile + A slices 0,1,2 ----
    {
        const unsigned short* xrow_base = xT + (size_t)b * NN * ROWE;
        #pragma unroll
        for (int s = 0; s < 16; ++s) {
            int W   = s * 512 + tid;            // 0..8191
            int r   = W >> 11;                  // 0..3
            int rem = W & 2047;                 // p*16 + j
            int grow = rp * 2 - 1 + r;          // -1..128
            int growc = grow < 0 ? 0 : (grow > NN - 1 ? NN - 1 : grow);
            // src chunk = (p+1)*16 + j = rem + 16  (skip pad col 0)
            gll16(xrow_base + (size_t)growc * ROWE + (size_t)(rem + 16) * 8,
                  xs + (size_t)W * 8);
        }
        gll16(kT2 + (size_t)tid * 8,             xs + (size_t)(XCH + tid) * 8);
        gll16(kT2 + (size_t)(ACH + tid) * 8,     xs + (size_t)(XCH + ACH + tid) * 8);
        gll16(kT2 + (size_t)(2 * ACH + tid) * 8, xs + (size_t)(XCH + 2 * ACH + tid) * 8);
    }
    asm volatile("s_waitcnt vmcnt(1)" ::: "memory");   // x + slices 0,1 landed; 2 flying
    __builtin_amdgcn_s_barrier();

    // ---- zero halo rows outside the image (block-uniform) ----
    if (rp == 0) {
        for (int W = tid; W < 2048; W += 512)
            *(short8*)(xs + (size_t)W * 8) = (short8)(0);
    }
    if (rp == 63) {
        for (int W = 3 * 2048 + tid; W < 4 * 2048; W += 512)
            *(short8*)(xs + (size_t)W * 8) = (short8)(0);
    }
    if (rp == 0 || rp == 63) {
        asm volatile("s_waitcnt lgkmcnt(0)" ::: "memory");
        __builtin_amdgcn_s_barrier();
    }

    float4v acc[4][4];
    #pragma unroll
    for (int m = 0; m < 4; ++m)
        #pragma unroll
        for (int n = 0; n < 4; ++n)
            acc[m][n] = (float4v)(0.0f);

    short8 aR[2][4], bR[2][4];

    // ---- load phase-0 fragments (kd=0 -> k=0,d=0; cc=0; A buf 0) ----
    {
        const unsigned short* ab = xs + (size_t)XCH * 8;
        #pragma unroll
        for (int m = 0; m < 4; ++m)
            aR[0][m] = *(const short8*)(ab + ((size_t)lg * 128 + ob + m * 16 + l15) * 8);
        const unsigned short* srow = xs + (size_t)wr * 2048 * 8;
        #pragma unroll
        for (int n = 0; n < 4; ++n) {
            int qq = pb + n * 16 + l15 - 1;
            int qc = qq < 0 ? 0 : (qq > 127 ? 127 : qq);
            int j  = lg ^ ((qc + 1) & 15);
            short8 v = *(const short8*)(srow + ((size_t)qc * 16 + j) * 8);
            bR[0][n] = (qq < 0) ? (short8)(0) : v;
        }
    }

    // ---- 36 phases; phase ph computes (kd=ph>>2, cc=ph&3) ----
    #pragma unroll
    for (int ph = 0; ph < 36; ++ph) {
        const int q = ph & 1;
        // issue gll16 of slice ph+3 (tail: dup slice 35, benign)
        {
            const int pn = (ph + 3 > 35) ? 35 : ph + 3;
            gll16(kT2 + ((size_t)pn * ACH + tid) * 8,
                  xs + (size_t)(XCH + (pn & 3) * ACH + tid) * 8);
        }
        // prefetch phase ph+1 fragments (slice ph+1 resident since end of ph-1)
        if (ph < 35) {
            const int p1  = ph + 1;
            const int kd1 = p1 >> 2, cc1 = p1 & 3;
            const int k1  = kd1 / 3, d1 = kd1 % 3;
            const unsigned short* ab = xs + (size_t)(XCH + (p1 & 3) * ACH) * 8;
            #pragma unroll
            for (int m = 0; m < 4; ++m)
                aR[q ^ 1][m] = *(const short8*)(ab + ((size_t)lg * 128 + ob + m * 16 + l15) * 8);
            const unsigned short* srow = xs + (size_t)(wr + k1) * 2048 * 8;
            #pragma unroll
            for (int n = 0; n < 4; ++n) {
                int qq = pb + n * 16 + l15 + d1 - 1;     // -1..128
                int qc = qq < 0 ? 0 : (qq > 127 ? 127 : qq);
                int j  = (cc1 * 4 + lg) ^ ((qc + 1) & 15);
                short8 v = *(const short8*)(srow + ((size_t)qc * 16 + j) * 8);
                bR[q ^ 1][n] = (qq < 0 || qq > 127) ? (short8)(0) : v;
            }
        }
        __builtin_amdgcn_s_setprio(1);
        #pragma unroll
        for (int m = 0; m < 4; ++m)
            #pragma unroll
            for (int n = 0; n < 4; ++n)
                acc[m][n] = __builtin_amdgcn_mfma_f32_16x16x32_bf16(aR[q][m], bR[q][n], acc[m][n], 0, 0, 0);
        __builtin_amdgcn_s_setprio(0);
        // slice ph+2 (issued at ph-1) must be resident for phase ph+1's prefetch
        asm volatile("s_waitcnt vmcnt(1)" ::: "memory");
        __builtin_amdgcn_s_barrier();
    }

    // store: D col = lane&15 -> px, row = (lane>>4)*4 + r -> o
    int row = rp * 2 + wr;
    float* op = out + (size_t)b * COUT * NN * NN + (size_t)row * NN;
    #pragma unroll
    for (int m = 0; m < 4; ++m) {
        #pragma unroll
        for (int n = 0; n < 4; ++n) {
            int p = pb + n * 16 + l15;
            #pragma unroll
            for (int r = 0; r < 4; ++r) {
                int o = ob + m * 16 + lg * 4 + r;
                op[(size_t)o * (NN * NN) + p] = acc[m][n][r];
            }
        }
    }
}

// ---------------------------------------------------------------------------
// fallback: naive direct conv (only if workspace too small)
// ---------------------------------------------------------------------------
__global__ __launch_bounds__(256) void conv_naive_kernel(const float* __restrict__ x,
                                                         const float* __restrict__ kern,
                                                         float* __restrict__ out) {
    size_t idx = (size_t)blockIdx.x * 256 + threadIdx.x;
    int p = idx & 127;
    size_t t = idx >> 7;
    int i = t & 127; t >>= 7;
    int o = t & 127;
    int b = (int)(t >> 7);
    float s = 0.f;
    for (int c = 0; c < CIN; ++c) {
        #pragma unroll
        for (int k = 0; k < 3; ++k) {
            int r = i + k - 1;
            if (r < 0 || r >= NN) continue;
            #pragma unroll
            for (int d = 0; d < 3; ++d) {
                int q = p + d - 1;
                if (q < 0 || q >= NN) continue;
                s += kern[(((size_t)o * CIN + c) * 3 + k) * 3 + d]
                   * x[(((size_t)b * CIN + c) * NN + r) * NN + q];
            }
        }
    }
    out[idx] = s;
}

extern "C" void kernel_launch(void* const* d_in, const int* in_sizes, int n_in,
                              void* d_out, int out_size, void* d_ws, size_t ws_size,
                              hipStream_t stream) {
    const float* x    = (const float*)d_in[0];
    const float* kern = (const float*)d_in[1];
    float* out = (float*)d_out;

    const size_t xT_bytes  = (size_t)B_ * NN * ROWE * 2;        // 136,314,880
    const size_t kT_bytes  = (size_t)9 * 16 * 128 * 8 * 2;      //     294,912

    if (ws_size >= xT_bytes + kT_bytes) {
        unsigned short* xT  = (unsigned short*)d_ws;
        unsigned short* kT2 = (unsigned short*)((char*)d_ws + xT_bytes);
        hipLaunchKernelGGL(xpose_kernel, dim3(B_ * NN), dim3(256), 0, stream, x, xT);
        hipLaunchKernelGGL(ktrans_kernel, dim3(576), dim3(256), 0, stream, kern, kT2);
        hipLaunchKernelGGL(conv_mfma9_kernel, dim3(2048), dim3(512), 0, stream, xT, kT2, out);
    } else {
        hipLaunchKernelGGL(conv_naive_kernel, dim3(67108864 / 256), dim3(256), 0, stream,
                           x, kern, out);
    }
}